// Round 9
// baseline (175.062 us; speedup 1.0000x reference)
//
#include <hip/hip_runtime.h>
#include <hip/hip_bf16.h>
#include <hip/hip_fp16.h>

#define DIM 512
#define BATCH 32
#define PLANE (BATCH * DIM * DIM)

typedef _Float16 half8 __attribute__((ext_vector_type(8)));
typedef float floatx4 __attribute__((ext_vector_type(4)));

static __device__ __forceinline__ unsigned short f2h(float f) {
    __half h = __float2half(f);
    return *reinterpret_cast<unsigned short*>(&h);
}

// ---------------------------------------------------------------------------
// Kernel 0: phase tables. pm[m] = e^{+i*kappa*m^2}, pj[j] = e^{-i*theta*j}.
// 1024 slow-path sincosf in parallel, once.
// ---------------------------------------------------------------------------
__global__ __launch_bounds__(256) void phase_tables(const float* __restrict__ th1p,
                                                    const float* __restrict__ th2p,
                                                    const float* __restrict__ kapp,
                                                    float2* __restrict__ pm,
                                                    float2* __restrict__ pj) {
    const int t = blockIdx.x * blockDim.x + threadIdx.x;
    if (t < DIM) {
        float s, c;
        sincosf(kapp[0] * (float)(t * t), &s, &c);
        pm[t] = make_float2(c, s);
    } else if (t < 2 * DIM) {
        const int j = t - DIM;
        float s, c;
        sincosf(-(th1p[0] + th2p[0]) * (float)j, &s, &c);
        pj[j] = make_float2(c, s);
    }
}

// ---------------------------------------------------------------------------
// Kernel 1: Taylor of expm(M/8), tridiagonal, one wave per row (r1-validated).
// ---------------------------------------------------------------------------
__global__ __launch_bounds__(256) void taylor_rows(const float* __restrict__ bxp,
                                                   const float* __restrict__ bpp,
                                                   float2* __restrict__ E) {
    const int wave = (blockIdx.x * blockDim.x + threadIdx.x) >> 6;
    const int lane = threadIdx.x & 63;
    if (wave >= DIM) return;
    const int i = wave;
    const float bx = bxp[0], bp = bpp[0];
    const float inv2s = 0.125f;
    const int o = lane - 31;
    const int j = i + o;
    const bool jvalid = (j >= 0 && j < DIM);

    float pre = 0.f, pim = 0.f;
    if (o == -1 && i >= 1)      { float g = sqrtf((float)i)       * inv2s; pre =  bx * g; pim = bp * g; }
    if (o ==  1 && i + 1 < DIM) { float g = sqrtf((float)(i + 1)) * inv2s; pre = -bx * g; pim = bp * g; }
    float ere = (o == 0 ? 1.f : 0.f) + pre;
    float eim = pim;

    const float gs = (jvalid && j >= 1)       ? sqrtf((float)j)       * inv2s : 0.f;
    const float hs = (jvalid && j + 1 < DIM)  ? sqrtf((float)(j + 1)) * inv2s : 0.f;
    const float csup_re = -bx * gs, csup_im = bp * gs;
    const float csub_re =  bx * hs, csub_im = bp * hs;

    for (int k = 2; k <= 24; ++k) {
        const float invk = 1.f / (float)k;
        float pmre = __shfl_up(pre, 1, 64),   pmim = __shfl_up(pim, 1, 64);
        float ppre = __shfl_down(pre, 1, 64), ppim = __shfl_down(pim, 1, 64);
        if (lane == 0)  { pmre = 0.f; pmim = 0.f; }
        if (lane == 63) { ppre = 0.f; ppim = 0.f; }
        float nre = pmre * csup_re - pmim * csup_im + ppre * csub_re - ppim * csub_im;
        float nim = pmre * csup_im + pmim * csup_re + ppre * csub_im + ppim * csub_re;
        pre = nre * invk; pim = nim * invk;
        ere += pre; eim += pim;
    }

    for (int base = 0; base < DIM; base += 64) {
        const int c = base + lane;
        const int src = c - i + 31;
        const float tre = __shfl(ere, src & 63, 64);
        const float tim = __shfl(eim, src & 63, 64);
        float vre = 0.f, vim = 0.f;
        if (src >= 0 && src < 64) { vre = tre; vim = tim; }
        E[i * DIM + c] = make_float2(vre, vim);
    }
}

// ---------------------------------------------------------------------------
// Kernel 2: band-aware complex square C = A*A (r1-validated).
// ---------------------------------------------------------------------------
__global__ __launch_bounds__(256) void csq(const float2* __restrict__ A,
                                           float2* __restrict__ C, int bIn) {
    __shared__ float2 At[16][64];
    __shared__ float2 Bt[16][64];
    const int j0 = blockIdx.x * 64, i0 = blockIdx.y * 64;
    const int tid = threadIdx.x;
    const int tx = tid & 15, ty = tid >> 4;
    const int lmin = max(0, max(i0, j0) - bIn);
    const int lmax = min(DIM, min(i0, j0) + 64 + bIn);

    float cre[4][4] = {{0.f}}, cim[4][4] = {{0.f}};
    for (int lt = lmin; lt < lmax; lt += 16) {
        for (int idx = tid; idx < 1024; idx += 256) {
            const int r = idx >> 4, c = idx & 15;
            const int l = lt + c;
            At[c][r] = (l < lmax) ? A[(i0 + r) * DIM + l] : make_float2(0.f, 0.f);
            const int rr = idx >> 6, cc = idx & 63;
            const int l2 = lt + rr;
            Bt[rr][cc] = (l2 < lmax) ? A[l2 * DIM + j0 + cc] : make_float2(0.f, 0.f);
        }
        __syncthreads();
        float are[4], aim[4], bre[4], bim[4];
#pragma unroll
        for (int ll = 0; ll < 16; ++ll) {
#pragma unroll
            for (int q = 0; q < 4; ++q) { float2 v = At[ll][ty * 4 + q]; are[q] = v.x; aim[q] = v.y; }
#pragma unroll
            for (int r = 0; r < 4; ++r) { float2 v = Bt[ll][tx * 4 + r]; bre[r] = v.x; bim[r] = v.y; }
#pragma unroll
            for (int q = 0; q < 4; ++q)
#pragma unroll
                for (int r = 0; r < 4; ++r) {
                    cre[q][r] += are[q] * bre[r] - aim[q] * bim[r];
                    cim[q][r] += are[q] * bim[r] + aim[q] * bre[r];
                }
        }
        __syncthreads();
    }
#pragma unroll
    for (int q = 0; q < 4; ++q)
#pragma unroll
        for (int r = 0; r < 4; ++r)
            C[(i0 + ty * 4 + q) * DIM + (j0 + tx * 4 + r)] = make_float2(cre[q][r], cim[q][r]);
}

// ---------------------------------------------------------------------------
// Kernel 2b: last squaring FUSED with phase fold (table-driven, no sincosf):
//   D = A*A;  D' = pm[m] * D[m][j] * pj[j]
//   Gp[m][2j] = fp16(Re D'), Gp[m][2j+1] = fp16(-Im D')
// ---------------------------------------------------------------------------
__global__ __launch_bounds__(256) void csq_fold(const float2* __restrict__ A,
                                                unsigned short* __restrict__ Gp,
                                                const float2* __restrict__ pm,
                                                const float2* __restrict__ pj,
                                                int bIn) {
    __shared__ float2 At[16][64];
    __shared__ float2 Bt[16][64];
    const int j0 = blockIdx.x * 64, i0 = blockIdx.y * 64;
    const int tid = threadIdx.x;
    const int tx = tid & 15, ty = tid >> 4;
    const int lmin = max(0, max(i0, j0) - bIn);
    const int lmax = min(DIM, min(i0, j0) + 64 + bIn);

    float cre[4][4] = {{0.f}}, cim[4][4] = {{0.f}};
    for (int lt = lmin; lt < lmax; lt += 16) {
        for (int idx = tid; idx < 1024; idx += 256) {
            const int r = idx >> 4, c = idx & 15;
            const int l = lt + c;
            At[c][r] = (l < lmax) ? A[(i0 + r) * DIM + l] : make_float2(0.f, 0.f);
            const int rr = idx >> 6, cc = idx & 63;
            const int l2 = lt + rr;
            Bt[rr][cc] = (l2 < lmax) ? A[l2 * DIM + j0 + cc] : make_float2(0.f, 0.f);
        }
        __syncthreads();
        float are[4], aim[4], bre[4], bim[4];
#pragma unroll
        for (int ll = 0; ll < 16; ++ll) {
#pragma unroll
            for (int q = 0; q < 4; ++q) { float2 v = At[ll][ty * 4 + q]; are[q] = v.x; aim[q] = v.y; }
#pragma unroll
            for (int r = 0; r < 4; ++r) { float2 v = Bt[ll][tx * 4 + r]; bre[r] = v.x; bim[r] = v.y; }
#pragma unroll
            for (int q = 0; q < 4; ++q)
#pragma unroll
                for (int r = 0; r < 4; ++r) {
                    cre[q][r] += are[q] * bre[r] - aim[q] * bim[r];
                    cim[q][r] += are[q] * bim[r] + aim[q] * bre[r];
                }
        }
        __syncthreads();
    }

#pragma unroll
    for (int q = 0; q < 4; ++q) {
        const int m = i0 + ty * 4 + q;
        const float2 km = pm[m];
#pragma unroll
        for (int r = 0; r < 4; ++r) {
            const int j = j0 + tx * 4 + r;
            const float2 tj = pj[j];
            const float r1 = cre[q][r] * tj.x - cim[q][r] * tj.y;
            const float i1 = cre[q][r] * tj.y + cim[q][r] * tj.x;
            const float r2 = r1 * km.x - i1 * km.y;
            const float i2 = r1 * km.y + i1 * km.x;
            *reinterpret_cast<ushort2*>(Gp + (size_t)m * 1024 + 2 * j) =
                make_ushort2(f2h(r2), f2h(-i2));
        }
    }
}

// ---------------------------------------------------------------------------
// Kernel 3: X transpose+pack: Xt[b][k][2j+c] = fp16(x{re,im}[b][j][k]).
// ---------------------------------------------------------------------------
__global__ __launch_bounds__(256) void xt_build(const float* __restrict__ xre,
                                                const float* __restrict__ xim,
                                                unsigned short* __restrict__ Xt) {
    __shared__ ushort2 T[64][65];
    const int j0 = blockIdx.x * 64, k0 = blockIdx.y * 64, b = blockIdx.z;
    const int tid = threadIdx.x;

    for (int p = tid; p < 1024; p += 256) {
        const int jr = p >> 4, seg = p & 15, koff = seg * 4;
        const size_t base = ((size_t)b * DIM + j0 + jr) * DIM + k0 + koff;
        const float4 xr = *reinterpret_cast<const float4*>(xre + base);
        const float4 xi = *reinterpret_cast<const float4*>(xim + base);
        T[jr][koff + 0] = make_ushort2(f2h(xr.x), f2h(xi.x));
        T[jr][koff + 1] = make_ushort2(f2h(xr.y), f2h(xi.y));
        T[jr][koff + 2] = make_ushort2(f2h(xr.z), f2h(xi.z));
        T[jr][koff + 3] = make_ushort2(f2h(xr.w), f2h(xi.w));
    }
    __syncthreads();

    for (int p = tid; p < 1024; p += 256) {
        const int k = p >> 4, seg = p & 15;
        union { ushort2 u[4]; float4 v; } pk;
#pragma unroll
        for (int jj = 0; jj < 4; ++jj)
            pk.u[jj] = T[seg * 4 + jj][k];
        unsigned short* dst = Xt + ((size_t)b * DIM + k0 + k) * 1024 + 2 * (j0 + seg * 4);
        *reinterpret_cast<float4*>(dst) = pk.v;
    }
}

// ---------------------------------------------------------------------------
// Kernel 4: MFMA apply. out[b][m][k] = sum_Kd Gp[m][Kd] * Xt[b][k][Kd],
// band j in [m0-64, m0+192). fp16 in, fp32 acc/out. No LDS, no barriers.
// ---------------------------------------------------------------------------
__global__ __launch_bounds__(256) void apply_mfma(const unsigned short* __restrict__ Gp,
                                                  const unsigned short* __restrict__ Xt,
                                                  float* __restrict__ out) {
    const int k0 = blockIdx.x * 128, m0 = blockIdx.y * 128, b = blockIdx.z;
    const int tid = threadIdx.x, lane = tid & 63, w = tid >> 6;
    const int wr = w >> 1, wc = w & 1;
    const int lr = lane & 15, lk8 = (lane >> 4) * 8;

    const int jmin = max(0, m0 - 64);
    const int jmax = min(DIM, m0 + 128 + 64);
    const int Kd0 = 2 * jmin;
    const int steps = (2 * (jmax - jmin)) >> 5;

    const unsigned short* gp = Gp + (size_t)(m0 + wr * 64 + lr) * 1024 + Kd0 + lk8;
    const unsigned short* xp = Xt + ((size_t)b * DIM + k0 + wc * 64 + lr) * 1024 + Kd0 + lk8;

    floatx4 acc[4][4];
#pragma unroll
    for (int ms = 0; ms < 4; ++ms)
#pragma unroll
        for (int ns = 0; ns < 4; ++ns) {
            acc[ms][ns][0] = 0.f; acc[ms][ns][1] = 0.f;
            acc[ms][ns][2] = 0.f; acc[ms][ns][3] = 0.f;
        }

#pragma unroll 4
    for (int s = 0; s < steps; ++s) {
        half8 a[4], bb[4];
#pragma unroll
        for (int ms = 0; ms < 4; ++ms)
            a[ms] = *reinterpret_cast<const half8*>(gp + (size_t)ms * 16 * 1024 + s * 32);
#pragma unroll
        for (int ns = 0; ns < 4; ++ns)
            bb[ns] = *reinterpret_cast<const half8*>(xp + (size_t)ns * 16 * 1024 + s * 32);
#pragma unroll
        for (int ms = 0; ms < 4; ++ms)
#pragma unroll
            for (int ns = 0; ns < 4; ++ns)
                acc[ms][ns] = __builtin_amdgcn_mfma_f32_16x16x32_f16(a[ms], bb[ns], acc[ms][ns], 0, 0, 0);
    }

    const int crow = (lane >> 4) * 4;
#pragma unroll
    for (int ms = 0; ms < 4; ++ms) {
#pragma unroll
        for (int ns = 0; ns < 4; ++ns) {
            const int kk = k0 + wc * 64 + ns * 16 + lr;
#pragma unroll
            for (int e = 0; e < 4; ++e) {
                const int m = m0 + wr * 64 + ms * 16 + crow + e;
                out[((size_t)b * DIM + m) * DIM + kk] = acc[ms][ns][e];
            }
        }
    }
}

// ---------------------------------------------------------------------------
// Fallback (r7-validated fp32 path) used only if ws_size is too small.
// ---------------------------------------------------------------------------
__global__ __launch_bounds__(256) void fold_gt(const float2* __restrict__ D,
                                               float2* __restrict__ Gt,
                                               const float* __restrict__ th1p,
                                               const float* __restrict__ th2p,
                                               const float* __restrict__ kapp) {
    const int idx = blockIdx.x * blockDim.x + threadIdx.x;
    const int m = idx & (DIM - 1), j = idx >> 9;
    const float theta = th1p[0] + th2p[0];
    const float kap = kapp[0];
    const float2 d = D[m * DIM + j];
    float sj, cj, sm, cm;
    sincosf(-theta * (float)j, &sj, &cj);
    sincosf(kap * (float)(m * m), &sm, &cm);
    const float r1 = d.x * cj - d.y * sj;
    const float i1 = d.x * sj + d.y * cj;
    const float r2 = r1 * cm - i1 * sm;
    const float i2 = r1 * sm + i1 * cm;
    Gt[idx] = make_float2(r2, -i2);
}

#define BM 128
#define BK 128
__global__ __launch_bounds__(256) void apply_real(const float2* __restrict__ Gt,
                                                  const float* __restrict__ xre,
                                                  const float* __restrict__ xim,
                                                  float* __restrict__ out) {
    __shared__ float2 As[16][BM];
    __shared__ float2 Bs[16][BK];
    const int k0 = blockIdx.x * BK, m0 = blockIdx.y * BM, bz = blockIdx.z;
    const int tid = threadIdx.x;
    const int tx = tid & 15, ty = tid >> 4;
    const int jmin = max(0, m0 - 64);
    const int jmax = min(DIM, m0 + BM + 64);
    const size_t xbase = (size_t)bz * DIM * DIM;

    float acc[8][8] = {{0.f}};
    for (int jt = jmin; jt < jmax; jt += 16) {
        for (int idx = tid; idx < 16 * BM; idx += 256) {
            const int l = idx >> 7, c = idx & (BM - 1);
            As[l][c] = Gt[(size_t)(jt + l) * DIM + m0 + c];
            const size_t xo = xbase + (size_t)(jt + l) * DIM + k0 + c;
            Bs[l][c] = make_float2(xre[xo], xim[xo]);
        }
        __syncthreads();
#pragma unroll
        for (int l = 0; l < 16; ++l) {
            float ar[8], ai[8], br[8], bi[8];
#pragma unroll
            for (int q = 0; q < 8; ++q) { float2 v = As[l][ty + 16 * q]; ar[q] = v.x; ai[q] = v.y; }
#pragma unroll
            for (int r = 0; r < 8; ++r) { float2 v = Bs[l][tx + 16 * r]; br[r] = v.x; bi[r] = v.y; }
#pragma unroll
            for (int q = 0; q < 8; ++q)
#pragma unroll
                for (int r = 0; r < 8; ++r)
                    acc[q][r] += ar[q] * br[r] + ai[q] * bi[r];
        }
        __syncthreads();
    }
#pragma unroll
    for (int q = 0; q < 8; ++q) {
        const int m = m0 + ty + 16 * q;
        const size_t off = (size_t)((size_t)bz * DIM + m) * DIM + k0 + tx;
#pragma unroll
        for (int r = 0; r < 8; ++r)
            out[off + 16 * r] = acc[q][r];
    }
}

// ---------------------------------------------------------------------------
extern "C" void kernel_launch(void* const* d_in, const int* in_sizes, int n_in,
                              void* d_out, int out_size, void* d_ws, size_t ws_size,
                              hipStream_t stream) {
    const float* xre = (const float*)d_in[0];
    const float* xim = (const float*)d_in[1];
    const float* th1 = (const float*)d_in[2];
    const float* th2 = (const float*)d_in[3];
    // d_in[4] = r : squeezing generator is exactly zero -> S = I, unused.
    const float* bx  = (const float*)d_in[5];
    const float* bp  = (const float*)d_in[6];
    const float* kap = (const float*)d_in[7];
    float* out = (float*)d_out;

    char* ws = (char*)d_ws;
    float2* bufA = (float2*)ws;                                      // 2 MB
    float2* bufB = (float2*)(ws + 2u * 1024 * 1024);                 // 2 MB
    unsigned short* Gp = (unsigned short*)(ws + 4u * 1024 * 1024);   // 1 MB
    unsigned short* Xt = (unsigned short*)(ws + 5u * 1024 * 1024);   // 32 MB
    const size_t xt_bytes = (size_t)BATCH * DIM * 1024 * 2;
    float2* pm = (float2*)(ws + 5u * 1024 * 1024 + xt_bytes);        // 4 KB
    float2* pj = pm + DIM;                                           // 4 KB
    const size_t need = 5u * 1024 * 1024 + xt_bytes + 8192;

    if (ws_size >= need) {
        hipLaunchKernelGGL(phase_tables, dim3(4), dim3(256), 0, stream,
                           th1, th2, kap, pm, pj);
        hipLaunchKernelGGL(taylor_rows, dim3(128), dim3(256), 0, stream, bx, bp, bufA);
        hipLaunchKernelGGL(csq, dim3(8, 8), dim3(256), 0, stream, bufA, bufB, 16);
        hipLaunchKernelGGL(csq, dim3(8, 8), dim3(256), 0, stream, bufB, bufA, 24);
        hipLaunchKernelGGL(csq_fold, dim3(8, 8), dim3(256), 0, stream,
                           bufA, Gp, pm, pj, 40);
        hipLaunchKernelGGL(xt_build, dim3(8, 8, BATCH), dim3(256), 0, stream,
                           xre, xim, Xt);
        hipLaunchKernelGGL(apply_mfma, dim3(4, 4, BATCH), dim3(256), 0, stream,
                           Gp, Xt, out);
    } else {
        hipLaunchKernelGGL(taylor_rows, dim3(128), dim3(256), 0, stream, bx, bp, bufA);
        hipLaunchKernelGGL(csq, dim3(8, 8), dim3(256), 0, stream, bufA, bufB, 16);
        hipLaunchKernelGGL(csq, dim3(8, 8), dim3(256), 0, stream, bufB, bufA, 24);
        float2* bufC = (float2*)(ws + 4u * 1024 * 1024);             // fp32 Gt, 2 MB
        hipLaunchKernelGGL(csq, dim3(8, 8), dim3(256), 0, stream, bufA, bufB, 40);
        hipLaunchKernelGGL(fold_gt, dim3(DIM * DIM / 256), dim3(256), 0, stream,
                           bufB, bufC, th1, th2, kap);
        hipLaunchKernelGGL(apply_real, dim3(DIM / BK, DIM / BM, BATCH), dim3(256), 0, stream,
                           bufC, xre, xim, out);
    }
}

// Round 10
// 76.664 us; speedup vs baseline: 2.2835x; 2.2835x over previous
//
#include <hip/hip_runtime.h>
#include <hip/hip_bf16.h>
#include <hip/hip_fp16.h>

#define DIM 512
#define BATCH 32
#define PLANE (BATCH * DIM * DIM)

typedef _Float16 half8 __attribute__((ext_vector_type(8)));
typedef float floatx4 __attribute__((ext_vector_type(4)));

static __device__ __forceinline__ unsigned short f2h(float f) {
    __half h = __float2half(f);
    return *reinterpret_cast<unsigned short*>(&h);
}

// ---------------------------------------------------------------------------
// Kernel 0: phase tables. pm[m] = e^{+i*kappa*m^2}, pj[j] = e^{-i*theta*j}.
// ---------------------------------------------------------------------------
__global__ __launch_bounds__(256) void phase_tables(const float* __restrict__ th1p,
                                                    const float* __restrict__ th2p,
                                                    const float* __restrict__ kapp,
                                                    float2* __restrict__ pm,
                                                    float2* __restrict__ pj) {
    const int t = blockIdx.x * blockDim.x + threadIdx.x;
    if (t < DIM) {
        float s, c;
        sincosf(kapp[0] * (float)(t * t), &s, &c);
        pm[t] = make_float2(c, s);
    } else if (t < 2 * DIM) {
        const int j = t - DIM;
        float s, c;
        sincosf(-(th1p[0] + th2p[0]) * (float)j, &s, &c);
        pj[j] = make_float2(c, s);
    }
}

// ---------------------------------------------------------------------------
// Kernel 1: Taylor of expm(M*invs), tridiagonal, one wave per row.
// (structure bit-validated r1/r2 at invs=0.125; generalized scale/terms)
// ---------------------------------------------------------------------------
__global__ __launch_bounds__(256) void taylor_rows(const float* __restrict__ bxp,
                                                   const float* __restrict__ bpp,
                                                   float2* __restrict__ E,
                                                   float invs, int K) {
    const int wave = (blockIdx.x * blockDim.x + threadIdx.x) >> 6;
    const int lane = threadIdx.x & 63;
    if (wave >= DIM) return;
    const int i = wave;
    const float bx = bxp[0], bp = bpp[0];
    const int o = lane - 31;
    const int j = i + o;
    const bool jvalid = (j >= 0 && j < DIM);

    float pre = 0.f, pim = 0.f;
    if (o == -1 && i >= 1)      { float g = sqrtf((float)i)       * invs; pre =  bx * g; pim = bp * g; }
    if (o ==  1 && i + 1 < DIM) { float g = sqrtf((float)(i + 1)) * invs; pre = -bx * g; pim = bp * g; }
    float ere = (o == 0 ? 1.f : 0.f) + pre;
    float eim = pim;

    const float gs = (jvalid && j >= 1)       ? sqrtf((float)j)       * invs : 0.f;
    const float hs = (jvalid && j + 1 < DIM)  ? sqrtf((float)(j + 1)) * invs : 0.f;
    const float csup_re = -bx * gs, csup_im = bp * gs;
    const float csub_re =  bx * hs, csub_im = bp * hs;

    for (int k = 2; k <= K; ++k) {
        const float invk = 1.f / (float)k;
        float pmre = __shfl_up(pre, 1, 64),   pmim = __shfl_up(pim, 1, 64);
        float ppre = __shfl_down(pre, 1, 64), ppim = __shfl_down(pim, 1, 64);
        if (lane == 0)  { pmre = 0.f; pmim = 0.f; }
        if (lane == 63) { ppre = 0.f; ppim = 0.f; }
        float nre = pmre * csup_re - pmim * csup_im + ppre * csub_re - ppim * csub_im;
        float nim = pmre * csup_im + pmim * csup_re + ppre * csub_im + ppim * csub_re;
        pre = nre * invk; pim = nim * invk;
        ere += pre; eim += pim;
    }

    for (int base = 0; base < DIM; base += 64) {
        const int c = base + lane;
        const int src = c - i + 31;
        const float tre = __shfl(ere, src & 63, 64);
        const float tim = __shfl(eim, src & 63, 64);
        float vre = 0.f, vim = 0.f;
        if (src >= 0 && src < 64) { vre = tre; vim = tim; }
        E[i * DIM + c] = make_float2(vre, vim);
    }
}

// ---------------------------------------------------------------------------
// Kernel 2: SINGLE squaring fused with phase fold, 32x32 tiles (256 blocks).
//   D = E*E (E band <= +-32 by construction);  D' = pm[i] * D[i][j] * pj[j]
//   Gp[i][2j] = fp16(Re D'), Gp[i][2j+1] = fp16(-Im D')
// Padded LDS stride 33 kills the 16-way staging bank conflict.
// ---------------------------------------------------------------------------
__global__ __launch_bounds__(256) void csq_fold32(const float2* __restrict__ A,
                                                  unsigned short* __restrict__ Gp,
                                                  const float2* __restrict__ pm,
                                                  const float2* __restrict__ pj) {
    __shared__ float2 At[16][33];   // At[l][i']
    __shared__ float2 Bt[16][33];   // Bt[l][j']
    const int j0 = blockIdx.x * 32, i0 = blockIdx.y * 32;
    const int tid = threadIdx.x;
    const int tx = tid & 15, ty = tid >> 4;
    const int lmin = max(0, max(i0, j0) - 32);
    const int lmax = min(DIM, min(i0, j0) + 64);

    float cre[2][2] = {{0.f}}, cim[2][2] = {{0.f}};
    for (int lt = lmin; lt < lmax; lt += 16) {
        for (int idx = tid; idx < 512; idx += 256) {
            const int r = idx >> 4, c = idx & 15;
            const int l = lt + c;
            At[c][r] = (l < lmax) ? A[(i0 + r) * DIM + l]      : make_float2(0.f, 0.f);
            Bt[c][r] = (l < lmax) ? A[(size_t)l * DIM + j0 + r] : make_float2(0.f, 0.f);
        }
        __syncthreads();
#pragma unroll
        for (int ll = 0; ll < 16; ++ll) {
            float2 a0 = At[ll][ty * 2], a1 = At[ll][ty * 2 + 1];
            float2 b0 = Bt[ll][tx * 2], b1 = Bt[ll][tx * 2 + 1];
            cre[0][0] += a0.x * b0.x - a0.y * b0.y;  cim[0][0] += a0.x * b0.y + a0.y * b0.x;
            cre[0][1] += a0.x * b1.x - a0.y * b1.y;  cim[0][1] += a0.x * b1.y + a0.y * b1.x;
            cre[1][0] += a1.x * b0.x - a1.y * b0.y;  cim[1][0] += a1.x * b0.y + a1.y * b0.x;
            cre[1][1] += a1.x * b1.x - a1.y * b1.y;  cim[1][1] += a1.x * b1.y + a1.y * b1.x;
        }
        __syncthreads();
    }

#pragma unroll
    for (int q = 0; q < 2; ++q) {
        const int m = i0 + ty * 2 + q;
        const float2 km = pm[m];
#pragma unroll
        for (int r = 0; r < 2; ++r) {
            const int j = j0 + tx * 2 + r;
            const float2 tj = pj[j];
            const float r1 = cre[q][r] * tj.x - cim[q][r] * tj.y;
            const float i1 = cre[q][r] * tj.y + cim[q][r] * tj.x;
            const float r2 = r1 * km.x - i1 * km.y;
            const float i2 = r1 * km.y + i1 * km.x;
            *reinterpret_cast<ushort2*>(Gp + (size_t)m * 1024 + 2 * j) =
                make_ushort2(f2h(r2), f2h(-i2));
        }
    }
}

// ---------------------------------------------------------------------------
// Kernel 3: X transpose+pack: Xt[b][k][2j+c] = fp16(x{re,im}[b][j][k]).
// ---------------------------------------------------------------------------
__global__ __launch_bounds__(256) void xt_build(const float* __restrict__ xre,
                                                const float* __restrict__ xim,
                                                unsigned short* __restrict__ Xt) {
    __shared__ ushort2 T[64][65];
    const int j0 = blockIdx.x * 64, k0 = blockIdx.y * 64, b = blockIdx.z;
    const int tid = threadIdx.x;

    for (int p = tid; p < 1024; p += 256) {
        const int jr = p >> 4, seg = p & 15, koff = seg * 4;
        const size_t base = ((size_t)b * DIM + j0 + jr) * DIM + k0 + koff;
        const float4 xr = *reinterpret_cast<const float4*>(xre + base);
        const float4 xi = *reinterpret_cast<const float4*>(xim + base);
        T[jr][koff + 0] = make_ushort2(f2h(xr.x), f2h(xi.x));
        T[jr][koff + 1] = make_ushort2(f2h(xr.y), f2h(xi.y));
        T[jr][koff + 2] = make_ushort2(f2h(xr.z), f2h(xi.z));
        T[jr][koff + 3] = make_ushort2(f2h(xr.w), f2h(xi.w));
    }
    __syncthreads();

    for (int p = tid; p < 1024; p += 256) {
        const int k = p >> 4, seg = p & 15;
        union { ushort2 u[4]; float4 v; } pk;
#pragma unroll
        for (int jj = 0; jj < 4; ++jj)
            pk.u[jj] = T[seg * 4 + jj][k];
        unsigned short* dst = Xt + ((size_t)b * DIM + k0 + k) * 1024 + 2 * (j0 + seg * 4);
        *reinterpret_cast<float4*>(dst) = pk.v;
    }
}

// ---------------------------------------------------------------------------
// Kernel 4: MFMA apply. out[b][m][k] = sum_Kd Gp[m][Kd] * Xt[b][k][Kd],
// band j in [m0-64, m0+192). fp16 in, fp32 acc/out. No LDS, no barriers.
// ---------------------------------------------------------------------------
__global__ __launch_bounds__(256) void apply_mfma(const unsigned short* __restrict__ Gp,
                                                  const unsigned short* __restrict__ Xt,
                                                  float* __restrict__ out) {
    const int k0 = blockIdx.x * 128, m0 = blockIdx.y * 128, b = blockIdx.z;
    const int tid = threadIdx.x, lane = tid & 63, w = tid >> 6;
    const int wr = w >> 1, wc = w & 1;
    const int lr = lane & 15, lk8 = (lane >> 4) * 8;

    const int jmin = max(0, m0 - 64);
    const int jmax = min(DIM, m0 + 128 + 64);
    const int Kd0 = 2 * jmin;
    const int steps = (2 * (jmax - jmin)) >> 5;

    const unsigned short* gp = Gp + (size_t)(m0 + wr * 64 + lr) * 1024 + Kd0 + lk8;
    const unsigned short* xp = Xt + ((size_t)b * DIM + k0 + wc * 64 + lr) * 1024 + Kd0 + lk8;

    floatx4 acc[4][4];
#pragma unroll
    for (int ms = 0; ms < 4; ++ms)
#pragma unroll
        for (int ns = 0; ns < 4; ++ns) {
            acc[ms][ns][0] = 0.f; acc[ms][ns][1] = 0.f;
            acc[ms][ns][2] = 0.f; acc[ms][ns][3] = 0.f;
        }

#pragma unroll 4
    for (int s = 0; s < steps; ++s) {
        half8 a[4], bb[4];
#pragma unroll
        for (int ms = 0; ms < 4; ++ms)
            a[ms] = *reinterpret_cast<const half8*>(gp + (size_t)ms * 16 * 1024 + s * 32);
#pragma unroll
        for (int ns = 0; ns < 4; ++ns)
            bb[ns] = *reinterpret_cast<const half8*>(xp + (size_t)ns * 16 * 1024 + s * 32);
#pragma unroll
        for (int ms = 0; ms < 4; ++ms)
#pragma unroll
            for (int ns = 0; ns < 4; ++ns)
                acc[ms][ns] = __builtin_amdgcn_mfma_f32_16x16x32_f16(a[ms], bb[ns], acc[ms][ns], 0, 0, 0);
    }

    const int crow = (lane >> 4) * 4;
#pragma unroll
    for (int ms = 0; ms < 4; ++ms) {
#pragma unroll
        for (int ns = 0; ns < 4; ++ns) {
            const int kk = k0 + wc * 64 + ns * 16 + lr;
#pragma unroll
            for (int e = 0; e < 4; ++e) {
                const int m = m0 + wr * 64 + ms * 16 + crow + e;
                out[((size_t)b * DIM + m) * DIM + kk] = acc[ms][ns][e];
            }
        }
    }
}

// ---------------------------------------------------------------------------
// Fallback (r7-validated fp32 path) used only if ws_size is too small.
// ---------------------------------------------------------------------------
__global__ __launch_bounds__(256) void csq(const float2* __restrict__ A,
                                           float2* __restrict__ C, int bIn) {
    __shared__ float2 At[16][64];
    __shared__ float2 Bt[16][64];
    const int j0 = blockIdx.x * 64, i0 = blockIdx.y * 64;
    const int tid = threadIdx.x;
    const int tx = tid & 15, ty = tid >> 4;
    const int lmin = max(0, max(i0, j0) - bIn);
    const int lmax = min(DIM, min(i0, j0) + 64 + bIn);

    float cre[4][4] = {{0.f}}, cim[4][4] = {{0.f}};
    for (int lt = lmin; lt < lmax; lt += 16) {
        for (int idx = tid; idx < 1024; idx += 256) {
            const int r = idx >> 4, c = idx & 15;
            const int l = lt + c;
            At[c][r] = (l < lmax) ? A[(i0 + r) * DIM + l] : make_float2(0.f, 0.f);
            const int rr = idx >> 6, cc = idx & 63;
            const int l2 = lt + rr;
            Bt[rr][cc] = (l2 < lmax) ? A[l2 * DIM + j0 + cc] : make_float2(0.f, 0.f);
        }
        __syncthreads();
        float are[4], aim[4], bre[4], bim[4];
#pragma unroll
        for (int ll = 0; ll < 16; ++ll) {
#pragma unroll
            for (int q = 0; q < 4; ++q) { float2 v = At[ll][ty * 4 + q]; are[q] = v.x; aim[q] = v.y; }
#pragma unroll
            for (int r = 0; r < 4; ++r) { float2 v = Bt[ll][tx * 4 + r]; bre[r] = v.x; bim[r] = v.y; }
#pragma unroll
            for (int q = 0; q < 4; ++q)
#pragma unroll
                for (int r = 0; r < 4; ++r) {
                    cre[q][r] += are[q] * bre[r] - aim[q] * bim[r];
                    cim[q][r] += are[q] * bim[r] + aim[q] * bre[r];
                }
        }
        __syncthreads();
    }
#pragma unroll
    for (int q = 0; q < 4; ++q)
#pragma unroll
        for (int r = 0; r < 4; ++r)
            C[(i0 + ty * 4 + q) * DIM + (j0 + tx * 4 + r)] = make_float2(cre[q][r], cim[q][r]);
}

__global__ __launch_bounds__(256) void fold_gt(const float2* __restrict__ D,
                                               float2* __restrict__ Gt,
                                               const float* __restrict__ th1p,
                                               const float* __restrict__ th2p,
                                               const float* __restrict__ kapp) {
    const int idx = blockIdx.x * blockDim.x + threadIdx.x;
    const int m = idx & (DIM - 1), j = idx >> 9;
    const float theta = th1p[0] + th2p[0];
    const float kap = kapp[0];
    const float2 d = D[m * DIM + j];
    float sj, cj, sm, cm;
    sincosf(-theta * (float)j, &sj, &cj);
    sincosf(kap * (float)(m * m), &sm, &cm);
    const float r1 = d.x * cj - d.y * sj;
    const float i1 = d.x * sj + d.y * cj;
    const float r2 = r1 * cm - i1 * sm;
    const float i2 = r1 * sm + i1 * cm;
    Gt[idx] = make_float2(r2, -i2);
}

#define BM 128
#define BK 128
__global__ __launch_bounds__(256) void apply_real(const float2* __restrict__ Gt,
                                                  const float* __restrict__ xre,
                                                  const float* __restrict__ xim,
                                                  float* __restrict__ out) {
    __shared__ float2 As[16][BM];
    __shared__ float2 Bs[16][BK];
    const int k0 = blockIdx.x * BK, m0 = blockIdx.y * BM, bz = blockIdx.z;
    const int tid = threadIdx.x;
    const int tx = tid & 15, ty = tid >> 4;
    const int jmin = max(0, m0 - 64);
    const int jmax = min(DIM, m0 + BM + 64);
    const size_t xbase = (size_t)bz * DIM * DIM;

    float acc[8][8] = {{0.f}};
    for (int jt = jmin; jt < jmax; jt += 16) {
        for (int idx = tid; idx < 16 * BM; idx += 256) {
            const int l = idx >> 7, c = idx & (BM - 1);
            As[l][c] = Gt[(size_t)(jt + l) * DIM + m0 + c];
            const size_t xo = xbase + (size_t)(jt + l) * DIM + k0 + c;
            Bs[l][c] = make_float2(xre[xo], xim[xo]);
        }
        __syncthreads();
#pragma unroll
        for (int l = 0; l < 16; ++l) {
            float ar[8], ai[8], br[8], bi[8];
#pragma unroll
            for (int q = 0; q < 8; ++q) { float2 v = As[l][ty + 16 * q]; ar[q] = v.x; ai[q] = v.y; }
#pragma unroll
            for (int r = 0; r < 8; ++r) { float2 v = Bs[l][tx + 16 * r]; br[r] = v.x; bi[r] = v.y; }
#pragma unroll
            for (int q = 0; q < 8; ++q)
#pragma unroll
                for (int r = 0; r < 8; ++r)
                    acc[q][r] += ar[q] * br[r] + ai[q] * bi[r];
        }
        __syncthreads();
    }
#pragma unroll
    for (int q = 0; q < 8; ++q) {
        const int m = m0 + ty + 16 * q;
        const size_t off = (size_t)((size_t)bz * DIM + m) * DIM + k0 + tx;
#pragma unroll
        for (int r = 0; r < 8; ++r)
            out[off + 16 * r] = acc[q][r];
    }
}

// ---------------------------------------------------------------------------
extern "C" void kernel_launch(void* const* d_in, const int* in_sizes, int n_in,
                              void* d_out, int out_size, void* d_ws, size_t ws_size,
                              hipStream_t stream) {
    const float* xre = (const float*)d_in[0];
    const float* xim = (const float*)d_in[1];
    const float* th1 = (const float*)d_in[2];
    const float* th2 = (const float*)d_in[3];
    // d_in[4] = r : squeezing generator is exactly zero -> S = I, unused.
    const float* bx  = (const float*)d_in[5];
    const float* bp  = (const float*)d_in[6];
    const float* kap = (const float*)d_in[7];
    float* out = (float*)d_out;

    char* ws = (char*)d_ws;
    float2* bufA = (float2*)ws;                                      // 2 MB (E)
    float2* bufB = (float2*)(ws + 2u * 1024 * 1024);                 // 2 MB (fallback)
    unsigned short* Gp = (unsigned short*)(ws + 4u * 1024 * 1024);   // 1 MB
    unsigned short* Xt = (unsigned short*)(ws + 5u * 1024 * 1024);   // 32 MB
    const size_t xt_bytes = (size_t)BATCH * DIM * 1024 * 2;
    float2* pm = (float2*)(ws + 5u * 1024 * 1024 + xt_bytes);        // 4 KB
    float2* pj = pm + DIM;                                           // 4 KB
    const size_t need = 5u * 1024 * 1024 + xt_bytes + 8192;

    if (ws_size >= need) {
        hipLaunchKernelGGL(phase_tables, dim3(4), dim3(256), 0, stream,
                           th1, th2, kap, pm, pj);
        // E = expm(M/2): one wave-recurrence kernel (s=1, 30 terms)
        hipLaunchKernelGGL(taylor_rows, dim3(128), dim3(256), 0, stream,
                           bx, bp, bufA, 0.5f, 30);
        // D = E^2 fused with phase fold -> fp16 Gp  (256 blocks, 32x32 tiles)
        hipLaunchKernelGGL(csq_fold32, dim3(16, 16), dim3(256), 0, stream,
                           bufA, Gp, pm, pj);
        hipLaunchKernelGGL(xt_build, dim3(8, 8, BATCH), dim3(256), 0, stream,
                           xre, xim, Xt);
        hipLaunchKernelGGL(apply_mfma, dim3(4, 4, BATCH), dim3(256), 0, stream,
                           Gp, Xt, out);
    } else {
        hipLaunchKernelGGL(taylor_rows, dim3(128), dim3(256), 0, stream,
                           bx, bp, bufA, 0.125f, 24);
        hipLaunchKernelGGL(csq, dim3(8, 8), dim3(256), 0, stream, bufA, bufB, 16);
        hipLaunchKernelGGL(csq, dim3(8, 8), dim3(256), 0, stream, bufB, bufA, 24);
        float2* bufC = (float2*)(ws + 4u * 1024 * 1024);             // fp32 Gt, 2 MB
        hipLaunchKernelGGL(csq, dim3(8, 8), dim3(256), 0, stream, bufA, bufB, 40);
        hipLaunchKernelGGL(fold_gt, dim3(DIM * DIM / 256), dim3(256), 0, stream,
                           bufB, bufC, th1, th2, kap);
        hipLaunchKernelGGL(apply_real, dim3(DIM / BK, DIM / BM, BATCH), dim3(256), 0, stream,
                           bufC, xre, xim, out);
    }
}

// Round 11
// 57.157 us; speedup vs baseline: 3.0628x; 1.3413x over previous
//
#include <hip/hip_runtime.h>
#include <hip/hip_fp16.h>

#define DIM 512
#define BATCH 32

typedef _Float16 half8 __attribute__((ext_vector_type(8)));
typedef float floatx4 __attribute__((ext_vector_type(4)));

static __device__ __forceinline__ unsigned short f2h(float f) {
    __half h = __float2half(f);
    return *reinterpret_cast<unsigned short*>(&h);
}

// ---------------------------------------------------------------------------
// Kernel 1: Taylor of expm(M/2) (one wave per row, r1/r10-validated) + phase
// tables (block 128): pm[m] = e^{+i*kappa*m^2}, pj[j] = e^{-i*theta*j}.
// ---------------------------------------------------------------------------
__global__ __launch_bounds__(256) void taylor_tables(const float* __restrict__ bxp,
                                                     const float* __restrict__ bpp,
                                                     const float* __restrict__ th1p,
                                                     const float* __restrict__ th2p,
                                                     const float* __restrict__ kapp,
                                                     float2* __restrict__ E,
                                                     float2* __restrict__ pm,
                                                     float2* __restrict__ pj) {
    if (blockIdx.x == 128) {   // phase tables
        for (int u = threadIdx.x; u < 2 * DIM; u += 256) {
            if (u < DIM) {
                float s, c;
                sincosf(kapp[0] * (float)(u * u), &s, &c);
                pm[u] = make_float2(c, s);
            } else {
                const int j = u - DIM;
                float s, c;
                sincosf(-(th1p[0] + th2p[0]) * (float)j, &s, &c);
                pj[j] = make_float2(c, s);
            }
        }
        return;
    }

    const int wave = (blockIdx.x * blockDim.x + threadIdx.x) >> 6;
    const int lane = threadIdx.x & 63;
    if (wave >= DIM) return;
    const int i = wave;
    const float bx = bxp[0], bp = bpp[0];
    const float invs = 0.5f;   // s = 1 scaling
    const int o = lane - 31;
    const int j = i + o;
    const bool jvalid = (j >= 0 && j < DIM);

    float pre = 0.f, pim = 0.f;
    if (o == -1 && i >= 1)      { float g = sqrtf((float)i)       * invs; pre =  bx * g; pim = bp * g; }
    if (o ==  1 && i + 1 < DIM) { float g = sqrtf((float)(i + 1)) * invs; pre = -bx * g; pim = bp * g; }
    float ere = (o == 0 ? 1.f : 0.f) + pre;
    float eim = pim;

    const float gs = (jvalid && j >= 1)       ? sqrtf((float)j)       * invs : 0.f;
    const float hs = (jvalid && j + 1 < DIM)  ? sqrtf((float)(j + 1)) * invs : 0.f;
    const float csup_re = -bx * gs, csup_im = bp * gs;
    const float csub_re =  bx * hs, csub_im = bp * hs;

    for (int k = 2; k <= 30; ++k) {
        const float invk = 1.f / (float)k;
        float pmre = __shfl_up(pre, 1, 64),   pmim = __shfl_up(pim, 1, 64);
        float ppre = __shfl_down(pre, 1, 64), ppim = __shfl_down(pim, 1, 64);
        if (lane == 0)  { pmre = 0.f; pmim = 0.f; }
        if (lane == 63) { ppre = 0.f; ppim = 0.f; }
        float nre = pmre * csup_re - pmim * csup_im + ppre * csub_re - ppim * csub_im;
        float nim = pmre * csup_im + pmim * csup_re + ppre * csub_im + ppim * csub_re;
        pre = nre * invk; pim = nim * invk;
        ere += pre; eim += pim;
    }

    for (int base = 0; base < DIM; base += 64) {
        const int c = base + lane;
        const int src = c - i + 31;
        const float tre = __shfl(ere, src & 63, 64);
        const float tim = __shfl(eim, src & 63, 64);
        float vre = 0.f, vim = 0.f;
        if (src >= 0 && src < 64) { vre = tre; vim = tim; }
        E[i * DIM + c] = make_float2(vre, vim);
    }
}

// ---------------------------------------------------------------------------
// Kernel 2: single squaring fused with phase fold, 32x32 tiles (256 blocks).
//   D = E*E;  D' = pm[i] * D[i][j] * pj[j]
//   Gp[i][2j] = fp16(Re D'), Gp[i][2j+1] = fp16(-Im D')    (r10-validated)
// ---------------------------------------------------------------------------
__global__ __launch_bounds__(256) void csq_fold32(const float2* __restrict__ A,
                                                  unsigned short* __restrict__ Gp,
                                                  const float2* __restrict__ pm,
                                                  const float2* __restrict__ pj) {
    __shared__ float2 At[16][33];
    __shared__ float2 Bt[16][33];
    const int j0 = blockIdx.x * 32, i0 = blockIdx.y * 32;
    const int tid = threadIdx.x;
    const int tx = tid & 15, ty = tid >> 4;
    const int lmin = max(0, max(i0, j0) - 32);
    const int lmax = min(DIM, min(i0, j0) + 64);

    float cre[2][2] = {{0.f}}, cim[2][2] = {{0.f}};
    for (int lt = lmin; lt < lmax; lt += 16) {
        for (int idx = tid; idx < 512; idx += 256) {
            const int r = idx >> 4, c = idx & 15;
            const int l = lt + c;
            At[c][r] = (l < lmax) ? A[(i0 + r) * DIM + l]       : make_float2(0.f, 0.f);
            Bt[c][r] = (l < lmax) ? A[(size_t)l * DIM + j0 + r] : make_float2(0.f, 0.f);
        }
        __syncthreads();
#pragma unroll
        for (int ll = 0; ll < 16; ++ll) {
            float2 a0 = At[ll][ty * 2], a1 = At[ll][ty * 2 + 1];
            float2 b0 = Bt[ll][tx * 2], b1 = Bt[ll][tx * 2 + 1];
            cre[0][0] += a0.x * b0.x - a0.y * b0.y;  cim[0][0] += a0.x * b0.y + a0.y * b0.x;
            cre[0][1] += a0.x * b1.x - a0.y * b1.y;  cim[0][1] += a0.x * b1.y + a0.y * b1.x;
            cre[1][0] += a1.x * b0.x - a1.y * b0.y;  cim[1][0] += a1.x * b0.y + a1.y * b0.x;
            cre[1][1] += a1.x * b1.x - a1.y * b1.y;  cim[1][1] += a1.x * b1.y + a1.y * b1.x;
        }
        __syncthreads();
    }

#pragma unroll
    for (int q = 0; q < 2; ++q) {
        const int m = i0 + ty * 2 + q;
        const float2 km = pm[m];
#pragma unroll
        for (int r = 0; r < 2; ++r) {
            const int j = j0 + tx * 2 + r;
            const float2 tj = pj[j];
            const float r1 = cre[q][r] * tj.x - cim[q][r] * tj.y;
            const float i1 = cre[q][r] * tj.y + cim[q][r] * tj.x;
            const float r2 = r1 * km.x - i1 * km.y;
            const float i2 = r1 * km.y + i1 * km.x;
            *reinterpret_cast<ushort2*>(Gp + (size_t)m * 1024 + 2 * j) =
                make_ushort2(f2h(r2), f2h(-i2));
        }
    }
}

// ---------------------------------------------------------------------------
// Kernel 3: FUSED stage+MFMA apply (replaces xt_build + apply_mfma).
//   out[b][m][k] = sum_Kd Gp[m][Kd] * X[b][k][Kd],  Kd = 2j+c, j in band
//   [m0-64, m0+192). X is staged per 32-j chunk: fp32 global -> fp16 packed-Kd
//   LDS tile Xs[k=128][Kd=64] (stride 72 ushorts: staging writes conflict-free,
//   ds_read_b128 at its natural floor). MFMA mapping identical to r8-r10.
// ---------------------------------------------------------------------------
#define XS_STRIDE 72
__global__ __launch_bounds__(256) void apply_fused(const unsigned short* __restrict__ Gp,
                                                   const float* __restrict__ xre,
                                                   const float* __restrict__ xim,
                                                   float* __restrict__ out) {
    __shared__ unsigned short Xs[128 * XS_STRIDE];   // 36.9 KB

    const int k0 = blockIdx.x * 128, m0 = blockIdx.y * 128, b = blockIdx.z;
    const int tid = threadIdx.x, lane = tid & 63, w = tid >> 6;
    const int wr = w >> 1, wc = w & 1;
    const int lr = lane & 15, lk8 = (lane >> 4) * 8;

    const int jmin = max(0, m0 - 64);
    const int jmax = min(DIM, m0 + 192);
    const int nchunk = (jmax - jmin) >> 5;           // 6 or 8 chunks of 32 j

    // staging map: thread -> (local j row, 16-wide k segment)
    const int s_jl = tid & 31;
    const int s_k  = (tid >> 5) << 4;

    const unsigned short* gp = Gp + (size_t)(m0 + wr * 64 + lr) * 1024 + 2 * jmin + lk8;
    const unsigned short* bbase = &Xs[(wc * 64 + lr) * XS_STRIDE + lk8];

    floatx4 acc[4][4];
#pragma unroll
    for (int ms = 0; ms < 4; ++ms)
#pragma unroll
        for (int ns = 0; ns < 4; ++ns) {
            acc[ms][ns][0] = 0.f; acc[ms][ns][1] = 0.f;
            acc[ms][ns][2] = 0.f; acc[ms][ns][3] = 0.f;
        }

    for (int ch = 0; ch < nchunk; ++ch) {
        // ---- issue global loads early (latency hides under the barrier) ----
        const size_t xrow = ((size_t)b * DIM + jmin + ch * 32 + s_jl) * DIM + k0 + s_k;
        float4 xr[4], xi[4];
#pragma unroll
        for (int t = 0; t < 4; ++t) xr[t] = *reinterpret_cast<const float4*>(xre + xrow + 4 * t);
#pragma unroll
        for (int t = 0; t < 4; ++t) xi[t] = *reinterpret_cast<const float4*>(xim + xrow + 4 * t);

        __syncthreads();   // all waves done reading previous chunk's Xs

        // ---- pack fp16 + transpose into LDS: Xs[k][2*jl + {0,1}] ----
#pragma unroll
        for (int t = 0; t < 4; ++t) {
            const int kb = s_k + 4 * t;
            *reinterpret_cast<ushort2*>(&Xs[(kb + 0) * XS_STRIDE + 2 * s_jl]) = make_ushort2(f2h(xr[t].x), f2h(xi[t].x));
            *reinterpret_cast<ushort2*>(&Xs[(kb + 1) * XS_STRIDE + 2 * s_jl]) = make_ushort2(f2h(xr[t].y), f2h(xi[t].y));
            *reinterpret_cast<ushort2*>(&Xs[(kb + 2) * XS_STRIDE + 2 * s_jl]) = make_ushort2(f2h(xr[t].z), f2h(xi[t].z));
            *reinterpret_cast<ushort2*>(&Xs[(kb + 3) * XS_STRIDE + 2 * s_jl]) = make_ushort2(f2h(xr[t].w), f2h(xi[t].w));
        }
        __syncthreads();

        // ---- 2 K-steps of 32 Kd: A from global (L2-hot G), B from LDS ----
#pragma unroll
        for (int s = 0; s < 2; ++s) {
            half8 a[4], bb[4];
#pragma unroll
            for (int ms = 0; ms < 4; ++ms)
                a[ms] = *reinterpret_cast<const half8*>(gp + (size_t)ms * 16 * 1024 + ch * 64 + s * 32);
#pragma unroll
            for (int ns = 0; ns < 4; ++ns)
                bb[ns] = *reinterpret_cast<const half8*>(bbase + ns * 16 * XS_STRIDE + s * 32);
#pragma unroll
            for (int ms = 0; ms < 4; ++ms)
#pragma unroll
                for (int ns = 0; ns < 4; ++ns)
                    acc[ms][ns] = __builtin_amdgcn_mfma_f32_16x16x32_f16(a[ms], bb[ns], acc[ms][ns], 0, 0, 0);
        }
    }

    // ---- epilogue (r8-validated C/D mapping) ----
    const int crow = (lane >> 4) * 4;
#pragma unroll
    for (int ms = 0; ms < 4; ++ms) {
#pragma unroll
        for (int ns = 0; ns < 4; ++ns) {
            const int kk = k0 + wc * 64 + ns * 16 + lr;
#pragma unroll
            for (int e = 0; e < 4; ++e) {
                const int m = m0 + wr * 64 + ms * 16 + crow + e;
                out[((size_t)b * DIM + m) * DIM + kk] = acc[ms][ns][e];
            }
        }
    }
}

// ---------------------------------------------------------------------------
extern "C" void kernel_launch(void* const* d_in, const int* in_sizes, int n_in,
                              void* d_out, int out_size, void* d_ws, size_t ws_size,
                              hipStream_t stream) {
    const float* xre = (const float*)d_in[0];
    const float* xim = (const float*)d_in[1];
    const float* th1 = (const float*)d_in[2];
    const float* th2 = (const float*)d_in[3];
    // d_in[4] = r : squeezing generator is exactly zero -> S = I, unused.
    const float* bx  = (const float*)d_in[5];
    const float* bp  = (const float*)d_in[6];
    const float* kap = (const float*)d_in[7];
    float* out = (float*)d_out;

    char* ws = (char*)d_ws;
    float2* E           = (float2*)ws;                               // 2 MB
    unsigned short* Gp  = (unsigned short*)(ws + 2u * 1024 * 1024);  // 1 MB
    float2* pm          = (float2*)(ws + 3u * 1024 * 1024);          // 4 KB
    float2* pj          = pm + DIM;                                  // 4 KB

    // E = expm(M/2) + phase tables (129 blocks: 128 taylor + 1 tables)
    hipLaunchKernelGGL(taylor_tables, dim3(129), dim3(256), 0, stream,
                       bx, bp, th1, th2, kap, E, pm, pj);
    // D = E^2 fused with phase fold -> fp16 packed Gp
    hipLaunchKernelGGL(csq_fold32, dim3(16, 16), dim3(256), 0, stream,
                       E, Gp, pm, pj);
    // out = real(K * D'' @ x[b]) — fused stage+MFMA, fp32 out
    hipLaunchKernelGGL(apply_fused, dim3(4, 4, BATCH), dim3(256), 0, stream,
                       Gp, xre, xim, out);
}